// Round 19
// baseline (80.171 us; speedup 1.0000x reference)
//
#include <hip/hip_runtime.h>
#include <math.h>

#define NFFT   1024
#define FREQ   513
#define FRAMES 256
#define SIGLEN 66560          // 256*256 + 1024
#define NB     4
#define BFT    (NB * FREQ * FRAMES)   // 525312
#define NWAVE  4               // waves per block (n-loop split factor)
#define NTHR   (64 * NWAVE)    // 256
#define NCHUNK 9               // ceil(513/64)
#define UNITS  (NCHUNK * FRAMES)      // 2304 units (LPT: desc-theta chunks)
#define GRIDD  2048            // persistent blocks = 8/CU co-resident

typedef float f32x2 __attribute__((ext_vector_type(2)));

__device__ __forceinline__ float sigmoid_f32(float v)
{
    if (v >= 0.0f) {
        return 1.0f / (1.0f + expf(-v));
    } else {
        const float e = expf(v);
        return e / (1.0f + e);
    }
}

__device__ __forceinline__ float rfl_f32(float v)
{
    return __int_as_float(__builtin_amdgcn_readfirstlane(__float_as_int(v)));
}

// ---------------------------------------------------------------------------
// Setup: sorted-f (desc theta, stable), per-chunk theta-max, per-frame
// {base, center} tables, and the dynamic-work counter (init = GRIDD).
// ws layout (bytes): sf u16[513]@0, ctmax f32[9]@1028, tbase i32[256]@1064,
// tc f32[256]@2088, counter i32@3136 -> 3140 B total.
// ---------------------------------------------------------------------------
__global__ __launch_bounds__(1024)
void dstft_setup(const float* __restrict__ raw_win,
                 const float* __restrict__ raw_hop,
                 unsigned short* __restrict__ sf,
                 float* __restrict__ ctmax,
                 int* __restrict__ tbase,
                 float* __restrict__ tc,
                 int* __restrict__ counter)
{
    __shared__ float th[FREQ];
    const int tid = threadIdx.x;
    if (tid == 0) *counter = GRIDD;          // reset every launch
    if (tid < FREQ)
        th[tid] = 10.0f + sigmoid_f32(raw_win[tid]) * 1014.0f;
    __syncthreads();
    if (tid < FREQ) {
        const float ti = th[tid];
        int r = 0;
        for (int j = 0; j < FREQ; ++j) {
            const float tj = th[j];
            r += (tj > ti) || (tj == ti && j < tid);   // descending, stable
        }
        sf[r] = (unsigned short)tid;
        if ((r & 63) == 0) ctmax[r >> 6] = ti;         // chunk max (desc)
    }
    if (tid < FRAMES) {
        // f32-canonical replication of the reference pos computation
        const float hop = 1.0f + sigmoid_f32(raw_hop[0]) * 255.0f;
        float pos = (float)tid * hop;
        pos = fminf(fmaxf(pos, 0.0f), 65536.0f);
        const float fl = floorf(pos);
        tbase[tid] = (int)fl;
        tc[tid]    = 511.5f + (pos - fl);
    }
}

// ---------------------------------------------------------------------------
// PERSISTENT blocks + dynamic fetch: 2048 blocks (8/CU), block starts with
// unit blockIdx (desc-theta = LPT), then pulls units 2048..2303 from a global
// counter. Fetch issued before staging, consumed after epilogue (overlapped).
// Outputs are independent of which block runs which unit -> deterministic.
// Per unit: stage [lo,hi] x 4 batches into LDS float4 rows; 4 waves split
// support; packed-f32 inner loop; part[] aliases xlds; parallel epilogue.
// ---------------------------------------------------------------------------
__global__ __launch_bounds__(NTHR, 8)
void dstft_main(const float* __restrict__ x,
                const float* __restrict__ raw_win,
                const float* __restrict__ raw_hop,
                const unsigned short* __restrict__ sf,   // may be null
                const float* __restrict__ ctmax,
                const int* __restrict__ tbase,
                const float* __restrict__ tc,
                int* __restrict__ counter,               // may be null
                float* __restrict__ out, int out_size, int stft_mode)
{
    const int tid  = threadIdx.x;
    const int lane = tid & 63;
    const int q    = tid >> 6;               // wave id = n-segment = batch

    __shared__ __align__(16) unsigned char smem[NFFT * sizeof(float4)]; //16KB
    float4* xlds = reinterpret_cast<float4*>(smem);
    float (*part)[64][9] = reinterpret_cast<float (*)[64][9]>(smem);
    __shared__ int u_next[2];

    const bool dyn = (counter != nullptr);
    int u   = (int)blockIdx.x;
    int tog = 0;

    while (u < UNITS) {
        // issue next-unit fetch early; consumed after the epilogue
        if (dyn && tid == 0) u_next[tog] = atomicAdd(counter, 1);

        const int chunk = u >> 8;            // 0..8 (desc-theta order)
        const int t     = u & 255;
        const int spos  = chunk * 64 + lane;
        const bool active = (spos < FREQ);

        int   f = 0;
        float theta, tmax, c;
        int   base;

        if (sf) {
            if (active) {
                f = (int)sf[spos];
                f = (f < 0) ? 0 : ((f > FREQ - 1) ? (FREQ - 1) : f);
            }
            theta = active ? (10.0f + sigmoid_f32(raw_win[f]) * 1014.0f)
                           : 10.0f;
            tmax  = rfl_f32(ctmax[chunk]);
            base  = __builtin_amdgcn_readfirstlane(tbase[t]);
            c     = rfl_f32(tc[t]);
        } else {
            // fallback (no ws): natural f order, inline params
            if (active) f = spos;
            theta = active ? (10.0f + sigmoid_f32(raw_win[f]) * 1014.0f)
                           : 10.0f;
            float tmaxv = theta;
#pragma unroll
            for (int s = 32; s; s >>= 1)
                tmaxv = fmaxf(tmaxv, __shfl_xor(tmaxv, s, 64));
            tmax = rfl_f32(tmaxv);
            const float hop = 1.0f + sigmoid_f32(raw_hop[0]) * 255.0f;
            float pos = (float)t * hop;
            pos = fminf(fmaxf(pos, 0.0f), 65536.0f);
            const float fl = floorf(pos);
            base = __builtin_amdgcn_readfirstlane((int)fl);
            c    = rfl_f32(511.5f + (pos - fl));
        }

        int lo = (int)floorf(c - 0.5f * tmax);
        int hi = (int)ceilf (c + 0.5f * tmax);
        lo = lo > 0 ? lo : 0;
        hi = hi < (NFFT - 1) ? hi : (NFFT - 1);
        int cnt = hi - lo + 1;
        cnt = cnt < 0 ? 0 : (cnt > NFFT ? NFFT : cnt);
        lo  = __builtin_amdgcn_readfirstlane(lo);
        cnt = __builtin_amdgcn_readfirstlane(cnt);

        // B0: prior epilogue's part[] reads done before xlds overwrite
        __syncthreads();

        // ---- stage x tile [lo, lo+cnt) into LDS (coalesced) ----
        for (int n = lo + tid; n < lo + cnt; n += NTHR) {
            float4 v;
            v.x = x[base + n];
            v.y = x[base + n + SIGLEN];
            v.z = x[base + n + 2 * SIGLEN];
            v.w = x[base + n + 3 * SIGLEN];
            xlds[n - lo] = v;
        }
        __syncthreads();                     // B1: xlds ready

        const int s0     = lo + (cnt * q) / NWAVE;
        const int s1     = lo + (cnt * (q + 1)) / NWAVE;
        const int segcnt = s1 - s0;

        const float invth = 1.0f / theta;
        float r = ((float)s0 - c) * invth;   // window arg, revolutions

        // phasor init at n=s0 and step: exact int reduction + hw trig (rev)
        const float sdr = (float)f * (1.0f / 1024.0f);
        const float cd  = __builtin_amdgcn_cosf(sdr);
        const float sd  = __builtin_amdgcn_sinf(sdr);
        int m0 = (f * s0) & (NFFT - 1);
        m0 = (m0 >= 512) ? (m0 - 1024) : m0;
        const float p0 = (float)m0 * (1.0f / 1024.0f);

        f32x2 p;                              // {ca, sa}
        p.x = __builtin_amdgcn_cosf(p0);
        p.y = __builtin_amdgcn_sinf(p0);
        const f32x2 cdv = { cd,  cd };
        const f32x2 sdv = { -sd, sd };

        // batch-packed accumulators: {b0,b1},{b2,b3} for re and im-sum
        f32x2 are01 = {0.f, 0.f}, are23 = {0.f, 0.f};
        f32x2 aim01 = {0.f, 0.f}, aim23 = {0.f, 0.f};

        const float4* __restrict__ xp = &xlds[s0 - lo];
#pragma unroll 4
        for (int i = 0; i < segcnt; ++i) {
            // med3 clamp; cos(2*pi*(+-0.5)) = -1 -> w = 0 outside support
            const float rc = __builtin_amdgcn_fmed3f(r, -0.5f, 0.5f);
            const float w  = fmaf(0.5f, __builtin_amdgcn_cosf(rc), 0.5f);
            const float wc  = w * p.x;
            const float wsn = w * p.y;
            const f32x2 wcv = { wc,  wc  };
            const f32x2 wsv = { wsn, wsn };
            const float4 v = xp[i];           // ds_read_b128 broadcast
            const f32x2 v01 = { v.x, v.y };   // free halves of the load
            const f32x2 v23 = { v.z, v.w };
            are01 = __builtin_elementwise_fma(v01, wcv, are01);  // v_pk_fma
            are23 = __builtin_elementwise_fma(v23, wcv, are23);
            aim01 = __builtin_elementwise_fma(v01, wsv, aim01);
            aim23 = __builtin_elementwise_fma(v23, wsv, aim23);
            const f32x2 ps = p.yx;
            p = __builtin_elementwise_fma(p, cdv, ps * sdv);     // rotate
            r += invth;
        }

        __syncthreads();                     // B2: xlds reads done
        part[q][lane][0] = are01.x;  part[q][lane][1] = are01.y;
        part[q][lane][2] = are23.x;  part[q][lane][3] = are23.y;
        part[q][lane][4] = aim01.x;  part[q][lane][5] = aim01.y;
        part[q][lane][6] = aim23.x;  part[q][lane][7] = aim23.y;
        __syncthreads();                     // B3: part ready, u_next visible

        // ---- epilogue: 4 waves in parallel, thread = (lane, batch=q) ----
        if (active) {
            float res = 0.f, sms = 0.f;
#pragma unroll
            for (int pw = 0; pw < NWAVE; ++pw) {
                res += part[pw][lane][q];
                sms += part[pw][lane][4 + q];
            }
            const float re = res;
            const float im = -sms;
            const int idx = q * (FREQ * FRAMES) + f * FRAMES + t;
            if (idx < out_size)
                out[idx] = sqrtf(fmaf(re, re, im * im)) + 1e-12f;   // spec
            if (stft_mode == 2) {
                if (BFT + 2 * idx + 1 < out_size) {
                    out[BFT + 2 * idx]     = re;
                    out[BFT + 2 * idx + 1] = im;
                }
            } else {
                if (BFT + idx < out_size)
                    out[BFT + idx] = re;     // complex stored as f32 real
            }
        }

        if (!dyn) break;                     // static fallback: one unit
        u = u_next[tog];                     // fetched during this unit
        tog ^= 1;
    }
}

// ---------------------------------------------------------------------------
extern "C" void kernel_launch(void* const* d_in, const int* in_sizes, int n_in,
                              void* d_out, int out_size, void* d_ws, size_t ws_size,
                              hipStream_t stream)
{
    const float* x       = (const float*)d_in[0];
    const float* raw_win = (const float*)d_in[1];
    const float* raw_hop = (const float*)d_in[2];
    float* out = (float*)d_out;

    unsigned short* sf    = nullptr;
    float*          ctmax = nullptr;
    int*            tbase = nullptr;
    float*          tc    = nullptr;
    int*            cnt   = nullptr;
    if (d_ws != nullptr && ws_size >= 3200) {
        sf    = (unsigned short*)d_ws;                   // 1028 B
        ctmax = (float*)((char*)d_ws + 1028);            // 36 B
        tbase = (int*)  ((char*)d_ws + 1064);            // 1024 B
        tc    = (float*)((char*)d_ws + 2088);            // 1024 B (end 3112)
        cnt   = (int*)  ((char*)d_ws + 3136);            // 4 B
        dstft_setup<<<1, 1024, 0, stream>>>(raw_win, raw_hop,
                                            sf, ctmax, tbase, tc, cnt);
    }
    const int stft_mode = (out_size >= 3 * BFT) ? 2 : 1;
    const int grid = cnt ? GRIDD : UNITS;
    dstft_main<<<grid, NTHR, 0, stream>>>(
        x, raw_win, raw_hop, sf, ctmax, tbase, tc, cnt,
        out, out_size, stft_mode);
}

// Round 20
// 56.744 us; speedup vs baseline: 1.4128x; 1.4128x over previous
//
#include <hip/hip_runtime.h>
#include <math.h>

#define NFFT   1024
#define FREQ   513
#define FRAMES 256
#define SIGLEN 66560          // 256*256 + 1024
#define NB     4
#define BFT    (NB * FREQ * FRAMES)   // 525312
#define NWAVE  4               // waves per block (n-loop split factor)
#define NTHR   (64 * NWAVE)    // 256
#define NCHUNK 9               // ceil(513/64)
#define UNITS  (NCHUNK * FRAMES)      // 2304 blocks, 1 unit each (LPT order)

typedef float f32x2 __attribute__((ext_vector_type(2)));

__device__ __forceinline__ float sigmoid_f32(float v)
{
    if (v >= 0.0f) {
        return 1.0f / (1.0f + expf(-v));
    } else {
        const float e = expf(v);
        return e / (1.0f + e);
    }
}

__device__ __forceinline__ float rfl_f32(float v)
{
    return __int_as_float(__builtin_amdgcn_readfirstlane(__float_as_int(v)));
}

// ---------------------------------------------------------------------------
// Setup: sorted-f (desc theta, stable), per-chunk theta-max, per-frame
// {base, center} tables. ws layout (bytes): sf u16[513]@0, ctmax f32[9]@1028,
// tbase i32[256]@1064, tc f32[256]@2088 -> 3112 B total.
// ---------------------------------------------------------------------------
__global__ __launch_bounds__(1024)
void dstft_setup(const float* __restrict__ raw_win,
                 const float* __restrict__ raw_hop,
                 unsigned short* __restrict__ sf,
                 float* __restrict__ ctmax,
                 int* __restrict__ tbase,
                 float* __restrict__ tc)
{
    __shared__ float th[FREQ];
    const int tid = threadIdx.x;
    if (tid < FREQ)
        th[tid] = 10.0f + sigmoid_f32(raw_win[tid]) * 1014.0f;
    __syncthreads();
    if (tid < FREQ) {
        const float ti = th[tid];
        int r = 0;
        for (int j = 0; j < FREQ; ++j) {
            const float tj = th[j];
            r += (tj > ti) || (tj == ti && j < tid);   // descending, stable
        }
        sf[r] = (unsigned short)tid;
        if ((r & 63) == 0) ctmax[r >> 6] = ti;         // chunk max (desc)
    }
    if (tid < FRAMES) {
        // f32-canonical replication of the reference pos computation
        const float hop = 1.0f + sigmoid_f32(raw_hop[0]) * 255.0f;
        float pos = (float)tid * hop;
        pos = fminf(fmaxf(pos, 0.0f), 65536.0f);
        const float fl = floorf(pos);
        tbase[tid] = (int)fl;
        tc[tid]    = 511.5f + (pos - fl);
    }
}

// ---------------------------------------------------------------------------
// Champion shell (r13): 2304 blocks (LPT desc-theta order), 4 waves, ONE
// unit each. x staged into LDS float4 rows over [lo,hi]; part[] aliases xlds
// (sync-separated) => 16.4 KB LDS. Inner loop: batch-packed f32x2 (v01/v23
// are free halves of ds_read_b128). Prologue params from d_ws tables.
// ---------------------------------------------------------------------------
__global__ __launch_bounds__(NTHR, 8)
void dstft_main(const float* __restrict__ x,
                const float* __restrict__ raw_win,
                const float* __restrict__ raw_hop,
                const unsigned short* __restrict__ sf,   // may be null
                const float* __restrict__ ctmax,
                const int* __restrict__ tbase,
                const float* __restrict__ tc,
                float* __restrict__ out, int out_size, int stft_mode)
{
    const int tid  = threadIdx.x;
    const int lane = tid & 63;
    const int q    = tid >> 6;               // wave id = n-segment = batch

    __shared__ __align__(16) unsigned char smem[NFFT * sizeof(float4)]; //16KB
    float4* xlds = reinterpret_cast<float4*>(smem);
    float (*part)[64][9] = reinterpret_cast<float (*)[64][9]>(smem);

    const int u     = (int)blockIdx.x;
    const int chunk = u >> 8;                // 0..8 (desc-theta order)
    const int t     = u & 255;
    const int spos  = chunk * 64 + lane;
    const bool active = (spos < FREQ);

    int   f = 0;
    float theta, tmax, c;
    int   base;

    if (sf) {
        if (active) {
            f = (int)sf[spos];
            f = (f < 0) ? 0 : ((f > FREQ - 1) ? (FREQ - 1) : f);
        }
        theta = active ? (10.0f + sigmoid_f32(raw_win[f]) * 1014.0f) : 10.0f;
        tmax  = rfl_f32(ctmax[chunk]);
        base  = __builtin_amdgcn_readfirstlane(tbase[t]);
        c     = rfl_f32(tc[t]);
    } else {
        // fallback (no ws): natural f order, inline params
        if (active) f = spos;
        theta = active ? (10.0f + sigmoid_f32(raw_win[f]) * 1014.0f) : 10.0f;
        float tmaxv = theta;
#pragma unroll
        for (int s = 32; s; s >>= 1)
            tmaxv = fmaxf(tmaxv, __shfl_xor(tmaxv, s, 64));
        tmax = rfl_f32(tmaxv);
        const float hop = 1.0f + sigmoid_f32(raw_hop[0]) * 255.0f;
        float pos = (float)t * hop;
        pos = fminf(fmaxf(pos, 0.0f), 65536.0f);
        const float fl = floorf(pos);
        base = __builtin_amdgcn_readfirstlane((int)fl);
        c    = rfl_f32(511.5f + (pos - fl));
    }

    int lo = (int)floorf(c - 0.5f * tmax);
    int hi = (int)ceilf (c + 0.5f * tmax);
    lo = lo > 0 ? lo : 0;
    hi = hi < (NFFT - 1) ? hi : (NFFT - 1);
    int cnt = hi - lo + 1;
    cnt = cnt < 0 ? 0 : (cnt > NFFT ? NFFT : cnt);
    lo  = __builtin_amdgcn_readfirstlane(lo);
    cnt = __builtin_amdgcn_readfirstlane(cnt);

    // ---- stage x tile [lo, lo+cnt) into LDS (coalesced) ----
    for (int n = lo + tid; n < lo + cnt; n += NTHR) {
        float4 v;
        v.x = x[base + n];
        v.y = x[base + n + SIGLEN];
        v.z = x[base + n + 2 * SIGLEN];
        v.w = x[base + n + 3 * SIGLEN];
        xlds[n - lo] = v;
    }
    __syncthreads();

    const int s0     = lo + (cnt * q) / NWAVE;
    const int s1     = lo + (cnt * (q + 1)) / NWAVE;
    const int segcnt = s1 - s0;

    const float invth = 1.0f / theta;
    float r = ((float)s0 - c) * invth;       // window arg, revolutions

    // phasor init at n=s0 and step: exact int reduction + hw trig (rev)
    const float sdr = (float)f * (1.0f / 1024.0f);
    const float cd  = __builtin_amdgcn_cosf(sdr);
    const float sd  = __builtin_amdgcn_sinf(sdr);
    int m0 = (f * s0) & (NFFT - 1);
    m0 = (m0 >= 512) ? (m0 - 1024) : m0;
    const float p0 = (float)m0 * (1.0f / 1024.0f);

    f32x2 p;                                  // {ca, sa}
    p.x = __builtin_amdgcn_cosf(p0);
    p.y = __builtin_amdgcn_sinf(p0);
    const f32x2 cdv = { cd,  cd };
    const f32x2 sdv = { -sd, sd };

    // batch-packed accumulators: {b0,b1} and {b2,b3} for re and im-sum
    f32x2 are01 = {0.f, 0.f}, are23 = {0.f, 0.f};
    f32x2 aim01 = {0.f, 0.f}, aim23 = {0.f, 0.f};

    const float4* __restrict__ xp = &xlds[s0 - lo];
#pragma unroll 4
    for (int i = 0; i < segcnt; ++i) {
        // med3 clamp; cos(2*pi*(+-0.5)) = -1 -> w = 0 outside support
        const float rc = __builtin_amdgcn_fmed3f(r, -0.5f, 0.5f);
        const float w  = fmaf(0.5f, __builtin_amdgcn_cosf(rc), 0.5f);
        const float wc  = w * p.x;
        const float wsn = w * p.y;
        const f32x2 wcv = { wc,  wc  };       // 1 splat mov
        const f32x2 wsv = { wsn, wsn };       // 1 splat mov
        const float4 v = xp[i];               // ds_read_b128 broadcast
        const f32x2 v01 = { v.x, v.y };       // free: aligned halves of load
        const f32x2 v23 = { v.z, v.w };
        are01 = __builtin_elementwise_fma(v01, wcv, are01);   // v_pk_fma_f32
        are23 = __builtin_elementwise_fma(v23, wcv, are23);
        aim01 = __builtin_elementwise_fma(v01, wsv, aim01);
        aim23 = __builtin_elementwise_fma(v23, wsv, aim23);
        const f32x2 ps = p.yx;
        p = __builtin_elementwise_fma(p, cdv, ps * sdv);      // rotate
        r += invth;
    }

    // ---- cross-wave combine; part aliases xlds, fence reads first ----
    __syncthreads();
    part[q][lane][0] = are01.x;  part[q][lane][1] = are01.y;
    part[q][lane][2] = are23.x;  part[q][lane][3] = are23.y;
    part[q][lane][4] = aim01.x;  part[q][lane][5] = aim01.y;
    part[q][lane][6] = aim23.x;  part[q][lane][7] = aim23.y;
    __syncthreads();

    // ---- epilogue: 4 waves in parallel, thread = (lane, batch=q) ----
    if (active) {
        float res = 0.f, sms = 0.f;
#pragma unroll
        for (int pw = 0; pw < NWAVE; ++pw) {
            res += part[pw][lane][q];
            sms += part[pw][lane][4 + q];
        }
        const float re = res;
        const float im = -sms;
        const int idx = q * (FREQ * FRAMES) + f * FRAMES + t;
        if (idx < out_size)
            out[idx] = sqrtf(fmaf(re, re, im * im)) + 1e-12f;   // spec
        if (stft_mode == 2) {
            if (BFT + 2 * idx + 1 < out_size) {
                out[BFT + 2 * idx]     = re;
                out[BFT + 2 * idx + 1] = im;
            }
        } else {
            if (BFT + idx < out_size)
                out[BFT + idx] = re;         // complex stored as f32 real
        }
    }
}

// ---------------------------------------------------------------------------
extern "C" void kernel_launch(void* const* d_in, const int* in_sizes, int n_in,
                              void* d_out, int out_size, void* d_ws, size_t ws_size,
                              hipStream_t stream)
{
    const float* x       = (const float*)d_in[0];
    const float* raw_win = (const float*)d_in[1];
    const float* raw_hop = (const float*)d_in[2];
    float* out = (float*)d_out;

    unsigned short* sf    = nullptr;
    float*          ctmax = nullptr;
    int*            tbase = nullptr;
    float*          tc    = nullptr;
    if (d_ws != nullptr && ws_size >= 3200) {
        sf    = (unsigned short*)d_ws;                   // 1028 B
        ctmax = (float*)((char*)d_ws + 1028);            // 36 B
        tbase = (int*)  ((char*)d_ws + 1064);            // 1024 B
        tc    = (float*)((char*)d_ws + 2088);            // 1024 B (end 3112)
        dstft_setup<<<1, 1024, 0, stream>>>(raw_win, raw_hop,
                                            sf, ctmax, tbase, tc);
    }
    const int stft_mode = (out_size >= 3 * BFT) ? 2 : 1;
    dstft_main<<<UNITS, NTHR, 0, stream>>>(
        x, raw_win, raw_hop, sf, ctmax, tbase, tc, out, out_size, stft_mode);
}